// Round 1
// baseline (282.983 us; speedup 1.0000x reference)
//
#include <hip/hip_runtime.h>
#include <stdint.h>

#define M_TOTAL 32768   // B*T
#define NUMS    512
#define DIM     1024
#define TOPK    33

typedef __bf16 bf16_t;
typedef bf16_t bf16x8 __attribute__((ext_vector_type(8)));
typedef float  f32x4  __attribute__((ext_vector_type(4)));
typedef unsigned short ushort_t;

__device__ __forceinline__ ushort_t f2bf(float f) {
    union { float f; uint32_t u; } x; x.f = f;
    uint32_t r = x.u + 0x7FFFu + ((x.u >> 16) & 1u);
    return (ushort_t)(r >> 16);
}
__device__ __forceinline__ float bf2f(ushort_t u) {
    union { uint32_t u; float f; } x; x.u = ((uint32_t)u) << 16;
    return x.f;
}

// ---------------------------------------------------------------------------
// prep: mem fp32 [512][1024] -> memB bf16 [512][1024] and memT bf16 [1024][512]
// ---------------------------------------------------------------------------
__global__ void prep_kernel(const float* __restrict__ mem,
                            ushort_t* __restrict__ memB,
                            ushort_t* __restrict__ memT) {
    __shared__ float tile[32][33];
    const int bi = blockIdx.x;      // 0..15  (NUMS/32)
    const int bj = blockIdx.y;      // 0..31  (DIM/32)
    const int t  = threadIdx.x;     // 256
    const int r  = t >> 3;          // 0..31
    const int c4 = (t & 7) * 4;     // 0,4,...,28

    const float4 v = *(const float4*)(mem + (size_t)(bi * 32 + r) * DIM + bj * 32 + c4);
    ushort4 b;
    b.x = f2bf(v.x); b.y = f2bf(v.y); b.z = f2bf(v.z); b.w = f2bf(v.w);
    *(ushort4*)(memB + (size_t)(bi * 32 + r) * DIM + bj * 32 + c4) = b;
    tile[r][c4 + 0] = v.x; tile[r][c4 + 1] = v.y;
    tile[r][c4 + 2] = v.z; tile[r][c4 + 3] = v.w;
    __syncthreads();
    // transposed: row d = bj*32 + r, cols n = bi*32 + c4..c4+3
    ushort4 o;
    o.x = f2bf(tile[c4 + 0][r]); o.y = f2bf(tile[c4 + 1][r]);
    o.z = f2bf(tile[c4 + 2][r]); o.w = f2bf(tile[c4 + 3][r]);
    *(ushort4*)(memT + (size_t)(bj * 32 + r) * NUMS + bi * 32 + c4) = o;
}

// ---------------------------------------------------------------------------
// G1: att[64 rows][512] = sigmoid(data @ memB^T / 32); fused top-33 mean;
//     att written as bf16 to ws.
// 512 threads = 8 waves (2 wave-rows x 4 wave-cols); wave tile 32x128.
// LDS: staging A bf16[64][64] swizzled @0 (8KB), B bf16[512][64] swizzled @8192 (64KB)
//      then reused: att bf16 [64][512] row-major @0 (64KB).
// ---------------------------------------------------------------------------
#define CE(a, b) { float _mx = fmaxf(a, b), _mn = fminf(a, b); a = _mx; b = _mn; }

__global__ __launch_bounds__(512, 2)
void g1_kernel(const float* __restrict__ data,
               const ushort_t* __restrict__ memB,
               ushort_t* __restrict__ att,
               float* __restrict__ temporal) {
    __shared__ __align__(16) unsigned char smem[73728];
    const int t    = threadIdx.x;
    const int lane = t & 63;
    const int wid  = t >> 6;        // 0..7
    const int wr   = wid >> 2;      // 0..1 : 32 rows each
    const int wc   = wid & 3;       // 0..3 : 128 cols each
    const int m0   = blockIdx.x * 64;

    f32x4 zero = {0.f, 0.f, 0.f, 0.f};
    f32x4 acc[2][8];
#pragma unroll
    for (int m = 0; m < 2; ++m)
#pragma unroll
        for (int n = 0; n < 8; ++n) acc[m][n] = zero;

    const int sr = t >> 3;   // A stage: row 0..63
    const int sc = t & 7;    // A stage: 16B chunk 0..7

    for (int ks = 0; ks < DIM / 64; ++ks) {
        const int k0 = ks * 64;
        __syncthreads();
        // ---- stage A: data fp32 -> bf16, swizzled [64][64]
        {
            const float* src = data + (size_t)(m0 + sr) * DIM + k0 + sc * 8;
            const float4 v0 = *(const float4*)src;
            const float4 v1 = *(const float4*)(src + 4);
            union { ushort_t us[8]; uint4 v; } pk;
            pk.us[0] = f2bf(v0.x); pk.us[1] = f2bf(v0.y);
            pk.us[2] = f2bf(v0.z); pk.us[3] = f2bf(v0.w);
            pk.us[4] = f2bf(v1.x); pk.us[5] = f2bf(v1.y);
            pk.us[6] = f2bf(v1.z); pk.us[7] = f2bf(v1.w);
            *(uint4*)(smem + sr * 128 + ((sc ^ (sr & 7)) << 4)) = pk.v;
        }
        // ---- stage B: memB bf16 [512][BK=64], swizzled
#pragma unroll
        for (int i = 0; i < 8; ++i) {
            const int q = i * 512 + t;
            const int n = q >> 3, c = q & 7;
            const uint4 v = *(const uint4*)(memB + (size_t)n * DIM + k0 + c * 8);
            *(uint4*)(smem + 8192 + n * 128 + ((c ^ (n & 7)) << 4)) = v;
        }
        __syncthreads();
        // ---- MFMA
#pragma unroll
        for (int ki = 0; ki < 2; ++ki) {
            const int ch = ki * 4 + (lane >> 4);
            bf16x8 af[2], bfr[8];
#pragma unroll
            for (int m = 0; m < 2; ++m) {
                const int row = wr * 32 + m * 16 + (lane & 15);
                af[m] = *(const bf16x8*)(smem + row * 128 + ((ch ^ (row & 7)) << 4));
            }
#pragma unroll
            for (int n = 0; n < 8; ++n) {
                const int col = wc * 128 + n * 16 + (lane & 15);
                bfr[n] = *(const bf16x8*)(smem + 8192 + col * 128 + ((ch ^ (col & 7)) << 4));
            }
#pragma unroll
            for (int m = 0; m < 2; ++m)
#pragma unroll
                for (int n = 0; n < 8; ++n)
                    acc[m][n] = __builtin_amdgcn_mfma_f32_16x16x32_bf16(af[m], bfr[n], acc[m][n], 0, 0, 0);
        }
    }
    __syncthreads();
    // ---- epilogue: sigmoid -> att LDS bf16 [64][512] row-major
    ushort_t* lAtt = (ushort_t*)smem;
#pragma unroll
    for (int m = 0; m < 2; ++m)
#pragma unroll
        for (int n = 0; n < 8; ++n)
#pragma unroll
            for (int reg = 0; reg < 4; ++reg) {
                const int row = wr * 32 + m * 16 + (lane >> 4) * 4 + reg;
                const int col = wc * 128 + n * 16 + (lane & 15);
                const float x = acc[m][n][reg] * 0.03125f;   // /sqrt(1024)
                const float s = 1.0f / (1.0f + __expf(-x));
                lAtt[row * 512 + col] = f2bf(s);
            }
    __syncthreads();
    // ---- att -> global ws (coalesced)
#pragma unroll
    for (int i = 0; i < 8; ++i) {
        const int e = i * 4096 + t * 8;
        const uint4 v = *(const uint4*)(lAtt + e);
        *(uint4*)(att + (size_t)m0 * 512 + e) = v;
    }
    // ---- top-33 mean, one wave per row, 8 rows per wave
    for (int ri = 0; ri < 8; ++ri) {
        const int row = wid * 8 + ri;
        const uint4 rv = *(const uint4*)(lAtt + row * 512 + lane * 8);
        float v0 = bf2f((ushort_t)(rv.x & 0xFFFF)), v1 = bf2f((ushort_t)(rv.x >> 16));
        float v2 = bf2f((ushort_t)(rv.y & 0xFFFF)), v3 = bf2f((ushort_t)(rv.y >> 16));
        float v4 = bf2f((ushort_t)(rv.z & 0xFFFF)), v5 = bf2f((ushort_t)(rv.z >> 16));
        float v6 = bf2f((ushort_t)(rv.w & 0xFFFF)), v7 = bf2f((ushort_t)(rv.w >> 16));
        // Batcher odd-even merge sort, descending (v0 = max)
        CE(v0, v1) CE(v2, v3) CE(v4, v5) CE(v6, v7)
        CE(v0, v2) CE(v1, v3) CE(v4, v6) CE(v5, v7)
        CE(v1, v2) CE(v5, v6)
        CE(v0, v4) CE(v1, v5) CE(v2, v6) CE(v3, v7)
        CE(v2, v4) CE(v3, v5)
        CE(v1, v2) CE(v3, v4) CE(v5, v6)
        float sum = 0.f;
        for (int it = 0; it < TOPK; ++it) {
            const float cand = v0;
            float mx = cand;
            mx = fmaxf(mx, __shfl_xor(mx, 32));
            mx = fmaxf(mx, __shfl_xor(mx, 16));
            mx = fmaxf(mx, __shfl_xor(mx, 8));
            mx = fmaxf(mx, __shfl_xor(mx, 4));
            mx = fmaxf(mx, __shfl_xor(mx, 2));
            mx = fmaxf(mx, __shfl_xor(mx, 1));
            sum += mx;
            const unsigned long long msk = __ballot(cand == mx);
            const int win = __ffsll(msk) - 1;
            if (lane == win) {
                v0 = v1; v1 = v2; v2 = v3; v3 = v4;
                v4 = v5; v5 = v6; v6 = v7; v7 = -1e30f;
            }
        }
        if (lane == 0) temporal[m0 + row] = sum * (1.0f / 33.0f);
    }
}

// ---------------------------------------------------------------------------
// G2: augment[32768][1024] fp32 = att bf16 [32768][512] @ memT bf16 [1024][512]^T
// 128x128 tile, BK=64, 256 threads = 4 waves (2x2), wave tile 64x64.
// ---------------------------------------------------------------------------
__global__ __launch_bounds__(256, 2)
void g2_kernel(const ushort_t* __restrict__ att,
               const ushort_t* __restrict__ memT,
               float* __restrict__ aug) {
    __shared__ __align__(16) unsigned char smem[32768];
    const int t    = threadIdx.x;
    const int lane = t & 63;
    const int wid  = t >> 6;      // 0..3
    const int wr   = wid >> 1;    // 0..1
    const int wc   = wid & 1;     // 0..1
    const int bid  = blockIdx.x;  // 0..2047
    const int m0   = (bid >> 3) * 128;
    const int n0   = (bid & 7) * 128;

    f32x4 zero = {0.f, 0.f, 0.f, 0.f};
    f32x4 acc[4][4];
#pragma unroll
    for (int m = 0; m < 4; ++m)
#pragma unroll
        for (int n = 0; n < 4; ++n) acc[m][n] = zero;

    for (int ks = 0; ks < NUMS / 64; ++ks) {
        const int k0 = ks * 64;
        __syncthreads();
#pragma unroll
        for (int i = 0; i < 4; ++i) {          // A tile [128][64]
            const int q = i * 256 + t;
            const int r = q >> 3, c = q & 7;
            const uint4 v = *(const uint4*)(att + (size_t)(m0 + r) * NUMS + k0 + c * 8);
            *(uint4*)(smem + r * 128 + ((c ^ (r & 7)) << 4)) = v;
        }
#pragma unroll
        for (int i = 0; i < 4; ++i) {          // B tile [128][64]
            const int q = i * 256 + t;
            const int r = q >> 3, c = q & 7;
            const uint4 v = *(const uint4*)(memT + (size_t)(n0 + r) * NUMS + k0 + c * 8);
            *(uint4*)(smem + 16384 + r * 128 + ((c ^ (r & 7)) << 4)) = v;
        }
        __syncthreads();
#pragma unroll
        for (int ki = 0; ki < 2; ++ki) {
            const int ch = ki * 4 + (lane >> 4);
            bf16x8 af[4], bfr[4];
#pragma unroll
            for (int m = 0; m < 4; ++m) {
                const int row = wr * 64 + m * 16 + (lane & 15);
                af[m] = *(const bf16x8*)(smem + row * 128 + ((ch ^ (row & 7)) << 4));
            }
#pragma unroll
            for (int n = 0; n < 4; ++n) {
                const int col = wc * 64 + n * 16 + (lane & 15);
                bfr[n] = *(const bf16x8*)(smem + 16384 + col * 128 + ((ch ^ (col & 7)) << 4));
            }
#pragma unroll
            for (int m = 0; m < 4; ++m)
#pragma unroll
                for (int n = 0; n < 4; ++n)
                    acc[m][n] = __builtin_amdgcn_mfma_f32_16x16x32_bf16(af[m], bfr[n], acc[m][n], 0, 0, 0);
        }
    }
#pragma unroll
    for (int m = 0; m < 4; ++m)
#pragma unroll
        for (int n = 0; n < 4; ++n)
#pragma unroll
            for (int reg = 0; reg < 4; ++reg) {
                const int row = m0 + wr * 64 + m * 16 + (lane >> 4) * 4 + reg;
                const int col = n0 + wc * 64 + n * 16 + (lane & 15);
                aug[(size_t)row * DIM + col] = acc[m][n][reg];
            }
}

// ---------------------------------------------------------------------------
extern "C" void kernel_launch(void* const* d_in, const int* in_sizes, int n_in,
                              void* d_out, int out_size, void* d_ws, size_t ws_size,
                              hipStream_t stream) {
    const float* data = (const float*)d_in[0];   // [16,2048,1024]
    const float* mem  = (const float*)d_in[1];   // [512,1024]
    float* temporal = (float*)d_out;             // [32768]
    float* aug      = (float*)d_out + M_TOTAL;   // [32768,1024]

    ushort_t* memB = (ushort_t*)d_ws;                    // 512*1024 bf16 (1MB)
    ushort_t* memT = memB + (size_t)NUMS * DIM;          // 1024*512 bf16 (1MB)
    ushort_t* attw = memT + (size_t)DIM * NUMS;          // 32768*512 bf16 (32MB)

    prep_kernel<<<dim3(16, 32), 256, 0, stream>>>(mem, memB, memT);
    g1_kernel<<<M_TOTAL / 64, 512, 0, stream>>>(data, memB, attw, temporal);
    g2_kernel<<<(M_TOTAL / 128) * (DIM / 128), 256, 0, stream>>>(attw, memT, aug);
}

// Round 2
// 150.669 us; speedup vs baseline: 1.8782x; 1.8782x over previous
//
#include <hip/hip_runtime.h>
#include <stdint.h>

#define M_TOTAL 32768   // B*T
#define NUMS    512
#define DIM     1024
#define TOPK    33

typedef __bf16 bf16_t;
typedef bf16_t bf16x8 __attribute__((ext_vector_type(8)));
typedef float  f32x4  __attribute__((ext_vector_type(4)));
typedef unsigned short ushort_t;

__device__ __forceinline__ ushort_t f2bf(float f) {
    union { float f; uint32_t u; } x; x.f = f;
    uint32_t r = x.u + 0x7FFFu + ((x.u >> 16) & 1u);
    return (ushort_t)(r >> 16);
}
__device__ __forceinline__ float bf2f(uint32_t u) {
    union { uint32_t u; float f; } x; x.u = u << 16;
    return x.f;
}

// global_load_lds: linear LDS dest (wave-uniform base + lane*16), per-lane global src
#define GLDS16(g, l) __builtin_amdgcn_global_load_lds( \
    (const __attribute__((address_space(1))) void*)(g), \
    (__attribute__((address_space(3))) void*)(l), 16, 0, 0)

// ---------------------------------------------------------------------------
// prep: mem fp32 [512][1024] -> memB bf16 [512][1024] and memT bf16 [1024][512]
// ---------------------------------------------------------------------------
__global__ void prep_kernel(const float* __restrict__ mem,
                            ushort_t* __restrict__ memB,
                            ushort_t* __restrict__ memT) {
    __shared__ float tile[32][33];
    const int bi = blockIdx.x;      // 0..15  (NUMS/32)
    const int bj = blockIdx.y;      // 0..31  (DIM/32)
    const int t  = threadIdx.x;     // 256
    const int r  = t >> 3;          // 0..31
    const int c4 = (t & 7) * 4;     // 0,4,...,28

    const float4 v = *(const float4*)(mem + (size_t)(bi * 32 + r) * DIM + bj * 32 + c4);
    ushort4 b;
    b.x = f2bf(v.x); b.y = f2bf(v.y); b.z = f2bf(v.z); b.w = f2bf(v.w);
    *(ushort4*)(memB + (size_t)(bi * 32 + r) * DIM + bj * 32 + c4) = b;
    tile[r][c4 + 0] = v.x; tile[r][c4 + 1] = v.y;
    tile[r][c4 + 2] = v.z; tile[r][c4 + 3] = v.w;
    __syncthreads();
    ushort4 o;
    o.x = f2bf(tile[c4 + 0][r]); o.y = f2bf(tile[c4 + 1][r]);
    o.z = f2bf(tile[c4 + 2][r]); o.w = f2bf(tile[c4 + 3][r]);
    *(ushort4*)(memT + (size_t)(bj * 32 + r) * NUMS + bi * 32 + c4) = o;
}

// ---------------------------------------------------------------------------
// G1: att[64 rows][512] = sigmoid(data @ memB^T / 32); fused top-33 mean;
//     att written as bf16 to ws.
// 512 threads = 8 waves (2 wave-rows x 4 wave-cols); wave tile 32x128.
// LDS: A bf16[64][64] swizzled @0 (8KB), B bf16[512][64] @8192 (64KB, linear
//      dest via global_load_lds + pre-swizzled global source);
//      then reused: att bf16 [64][512] row-major @0 (64KB).
// ---------------------------------------------------------------------------
__global__ __launch_bounds__(512, 2)
void g1_kernel(const float* __restrict__ data,
               const ushort_t* __restrict__ memB,
               ushort_t* __restrict__ att,
               float* __restrict__ temporal) {
    __shared__ __align__(16) unsigned char smem[73728];
    const int t    = threadIdx.x;
    const int lane = t & 63;
    const int wid  = t >> 6;        // 0..7
    const int wr   = wid >> 2;      // 0..1 : 32 rows each
    const int wc   = wid & 3;       // 0..3 : 128 cols each
    const int m0   = blockIdx.x * 64;

    f32x4 zero = {0.f, 0.f, 0.f, 0.f};
    f32x4 acc[2][8];
#pragma unroll
    for (int m = 0; m < 2; ++m)
#pragma unroll
        for (int n = 0; n < 8; ++n) acc[m][n] = zero;

    const int sr = t >> 3;   // A stage: row 0..63
    const int sc = t & 7;    // A stage: 16B chunk 0..7

    // B stage via global_load_lds: wave wid covers rows wid*64..wid*64+63,
    // 8 segments of 1KB (8 rows each). Lane l -> row i*8 + (l>>3), slot l&7.
    // LDS slot cslot must hold global chunk cslot ^ (row&7); row&7 == l>>3.
    const int csrc = (lane & 7) ^ (lane >> 3);
    const ushort_t* bsrc0 = memB + (size_t)(wid * 64 + (lane >> 3)) * DIM + csrc * 8;
    unsigned char* bdst0 = smem + 8192 + wid * 8192;

    for (int ks = 0; ks < DIM / 64; ++ks) {
        const int k0 = ks * 64;
        __syncthreads();
        // ---- stage B first (async, overlaps with A convert)
#pragma unroll
        for (int i = 0; i < 8; ++i) {
            GLDS16(bsrc0 + k0 + (size_t)i * 8 * DIM, bdst0 + i * 1024);
        }
        // ---- stage A: data fp32 -> bf16, swizzled [64][64]
        {
            const float* src = data + (size_t)(m0 + sr) * DIM + k0 + sc * 8;
            const float4 v0 = *(const float4*)src;
            const float4 v1 = *(const float4*)(src + 4);
            union { ushort_t us[8]; uint4 v; } pk;
            pk.us[0] = f2bf(v0.x); pk.us[1] = f2bf(v0.y);
            pk.us[2] = f2bf(v0.z); pk.us[3] = f2bf(v0.w);
            pk.us[4] = f2bf(v1.x); pk.us[5] = f2bf(v1.y);
            pk.us[6] = f2bf(v1.z); pk.us[7] = f2bf(v1.w);
            *(uint4*)(smem + sr * 128 + ((sc ^ (sr & 7)) << 4)) = pk.v;
        }
        __syncthreads();
        // ---- MFMA
#pragma unroll
        for (int ki = 0; ki < 2; ++ki) {
            const int ch = ki * 4 + (lane >> 4);
            bf16x8 af[2], bfr[8];
#pragma unroll
            for (int m = 0; m < 2; ++m) {
                const int row = wr * 32 + m * 16 + (lane & 15);
                af[m] = *(const bf16x8*)(smem + row * 128 + ((ch ^ (row & 7)) << 4));
            }
#pragma unroll
            for (int n = 0; n < 8; ++n) {
                const int col = wc * 128 + n * 16 + (lane & 15);
                bfr[n] = *(const bf16x8*)(smem + 8192 + col * 128 + ((ch ^ (col & 7)) << 4));
            }
#pragma unroll
            for (int m = 0; m < 2; ++m)
#pragma unroll
                for (int n = 0; n < 8; ++n)
                    acc[m][n] = __builtin_amdgcn_mfma_f32_16x16x32_bf16(af[m], bfr[n], acc[m][n], 0, 0, 0);
        }
    }
    __syncthreads();
    // ---- epilogue: sigmoid -> att LDS bf16 [64][512] row-major
    ushort_t* lAtt = (ushort_t*)smem;
#pragma unroll
    for (int m = 0; m < 2; ++m)
#pragma unroll
        for (int n = 0; n < 8; ++n)
#pragma unroll
            for (int reg = 0; reg < 4; ++reg) {
                const int row = wr * 32 + m * 16 + (lane >> 4) * 4 + reg;
                const int col = wc * 128 + n * 16 + (lane & 15);
                const float x = acc[m][n][reg] * 0.03125f;   // /sqrt(1024)
                const float s = 1.0f / (1.0f + __expf(-x));
                lAtt[row * 512 + col] = f2bf(s);
            }
    __syncthreads();
    // ---- att -> global ws (coalesced)
#pragma unroll
    for (int i = 0; i < 8; ++i) {
        const int e = i * 4096 + t * 8;
        const uint4 v = *(const uint4*)(lAtt + e);
        *(uint4*)(att + (size_t)m0 * 512 + e) = v;
    }
    // ---- top-33 mean via ballot radix-select, 8 rows per wave.
    // bf16 codes of positive values are monotone in uint16 bits.
    for (int ri = 0; ri < 8; ++ri) {
        const int row = wid * 8 + ri;
        const uint4 rv = *(const uint4*)(lAtt + row * 512 + lane * 8);
        uint32_t u[8];
        u[0] = rv.x & 0xFFFFu; u[1] = rv.x >> 16;
        u[2] = rv.y & 0xFFFFu; u[3] = rv.y >> 16;
        u[4] = rv.z & 0xFFFFu; u[5] = rv.z >> 16;
        u[6] = rv.w & 0xFFFFu; u[7] = rv.w >> 16;
        // radix select: largest code t with count(u >= t) >= TOPK
        uint32_t tc = 0;
#pragma unroll
        for (int b = 15; b >= 0; --b) {
            const uint32_t cand = tc | (1u << b);
            int c = 0;
#pragma unroll
            for (int j = 0; j < 8; ++j)
                c += __popcll(__ballot(u[j] >= cand));
            if (c >= TOPK) tc = cand;
        }
        // sum of strictly-greater values + count
        float sgt = 0.f; int cgt = 0;
#pragma unroll
        for (int j = 0; j < 8; ++j) {
            if (u[j] > tc) { sgt += bf2f(u[j]); cgt++; }
        }
#pragma unroll
        for (int off = 32; off >= 1; off >>= 1) {
            sgt += __shfl_xor(sgt, off);
            cgt += __shfl_xor(cgt, off);
        }
        if (lane == 0) {
            temporal[m0 + row] = (sgt + (float)(TOPK - cgt) * bf2f(tc)) * (1.0f / 33.0f);
        }
    }
}

// ---------------------------------------------------------------------------
// G2: augment[32768][1024] fp32 = att bf16 [32768][512] @ memT bf16 [1024][512]^T
// 128x128 tile, BK=64, 256 threads = 4 waves (2x2), wave tile 64x64.
// ---------------------------------------------------------------------------
__global__ __launch_bounds__(256, 2)
void g2_kernel(const ushort_t* __restrict__ att,
               const ushort_t* __restrict__ memT,
               float* __restrict__ aug) {
    __shared__ __align__(16) unsigned char smem[32768];
    const int t    = threadIdx.x;
    const int lane = t & 63;
    const int wid  = t >> 6;      // 0..3
    const int wr   = wid >> 1;    // 0..1
    const int wc   = wid & 1;     // 0..1
    const int bid  = blockIdx.x;  // 0..2047
    const int m0   = (bid >> 3) * 128;
    const int n0   = (bid & 7) * 128;

    f32x4 zero = {0.f, 0.f, 0.f, 0.f};
    f32x4 acc[4][4];
#pragma unroll
    for (int m = 0; m < 4; ++m)
#pragma unroll
        for (int n = 0; n < 4; ++n) acc[m][n] = zero;

    for (int ks = 0; ks < NUMS / 64; ++ks) {
        const int k0 = ks * 64;
        __syncthreads();
#pragma unroll
        for (int i = 0; i < 4; ++i) {          // A tile [128][64]
            const int q = i * 256 + t;
            const int r = q >> 3, c = q & 7;
            const uint4 v = *(const uint4*)(att + (size_t)(m0 + r) * NUMS + k0 + c * 8);
            *(uint4*)(smem + r * 128 + ((c ^ (r & 7)) << 4)) = v;
        }
#pragma unroll
        for (int i = 0; i < 4; ++i) {          // B tile [128][64]
            const int q = i * 256 + t;
            const int r = q >> 3, c = q & 7;
            const uint4 v = *(const uint4*)(memT + (size_t)(n0 + r) * NUMS + k0 + c * 8);
            *(uint4*)(smem + 16384 + r * 128 + ((c ^ (r & 7)) << 4)) = v;
        }
        __syncthreads();
#pragma unroll
        for (int ki = 0; ki < 2; ++ki) {
            const int ch = ki * 4 + (lane >> 4);
            bf16x8 af[4], bfr[4];
#pragma unroll
            for (int m = 0; m < 4; ++m) {
                const int row = wr * 64 + m * 16 + (lane & 15);
                af[m] = *(const bf16x8*)(smem + row * 128 + ((ch ^ (row & 7)) << 4));
            }
#pragma unroll
            for (int n = 0; n < 4; ++n) {
                const int col = wc * 64 + n * 16 + (lane & 15);
                bfr[n] = *(const bf16x8*)(smem + 16384 + col * 128 + ((ch ^ (col & 7)) << 4));
            }
#pragma unroll
            for (int m = 0; m < 4; ++m)
#pragma unroll
                for (int n = 0; n < 4; ++n)
                    acc[m][n] = __builtin_amdgcn_mfma_f32_16x16x32_bf16(af[m], bfr[n], acc[m][n], 0, 0, 0);
        }
    }
#pragma unroll
    for (int m = 0; m < 4; ++m)
#pragma unroll
        for (int n = 0; n < 4; ++n)
#pragma unroll
            for (int reg = 0; reg < 4; ++reg) {
                const int row = m0 + wr * 64 + m * 16 + (lane >> 4) * 4 + reg;
                const int col = n0 + wc * 64 + n * 16 + (lane & 15);
                aug[(size_t)row * DIM + col] = acc[m][n][reg];
            }
}

// ---------------------------------------------------------------------------
extern "C" void kernel_launch(void* const* d_in, const int* in_sizes, int n_in,
                              void* d_out, int out_size, void* d_ws, size_t ws_size,
                              hipStream_t stream) {
    const float* data = (const float*)d_in[0];   // [16,2048,1024]
    const float* mem  = (const float*)d_in[1];   // [512,1024]
    float* temporal = (float*)d_out;             // [32768]
    float* aug      = (float*)d_out + M_TOTAL;   // [32768,1024]

    ushort_t* memB = (ushort_t*)d_ws;                    // 512*1024 bf16 (1MB)
    ushort_t* memT = memB + (size_t)NUMS * DIM;          // 1024*512 bf16 (1MB)
    ushort_t* attw = memT + (size_t)DIM * NUMS;          // 32768*512 bf16 (32MB)

    prep_kernel<<<dim3(16, 32), 256, 0, stream>>>(mem, memB, memT);
    g1_kernel<<<M_TOTAL / 64, 512, 0, stream>>>(data, memB, attw, temporal);
    g2_kernel<<<(M_TOTAL / 128) * (DIM / 128), 256, 0, stream>>>(attw, memT, aug);
}